// Round 1
// baseline (1140.081 us; speedup 1.0000x reference)
//
#include <hip/hip_runtime.h>
#include <hip/hip_bf16.h>

#define NUM_USER 100000
#define NUM_ITEM 50000
#define N_NODES  150000
#define EMBED_DIM 64
#define ALG 4
#define DIM_FEAT 512
#define NEDGE 1000000

// ---------------- degree count ----------------
__global__ __launch_bounds__(256) void count_kernel(const int* __restrict__ row, int* __restrict__ deg)
{
    int e = blockIdx.x * 256 + threadIdx.x;
    if (e < NEDGE) atomicAdd(&deg[row[e]], 1);
}

// ---------------- exclusive scan (single block, 1024 thr) ----------------
__global__ __launch_bounds__(1024) void scan_kernel(const int* __restrict__ deg, int* __restrict__ off, int n)
{
    __shared__ int wpart[17];
    const int tid = threadIdx.x;
    const int lane = tid & 63, w = tid >> 6;
    int running = 0;
    for (int base = 0; base < n; base += 1024) {
        int i = base + tid;
        int v = (i < n) ? deg[i] : 0;
        int x = v;
        #pragma unroll
        for (int d = 1; d < 64; d <<= 1) {
            int t = __shfl_up(x, d);
            if (lane >= d) x += t;
        }
        if (lane == 63) wpart[w] = x;
        __syncthreads();
        if (tid == 0) {
            int a = 0;
            #pragma unroll
            for (int j = 0; j < 16; ++j) { int t = wpart[j]; wpart[j] = a; a += t; }
            wpart[16] = a;
        }
        __syncthreads();
        if (i < n) off[i] = running + wpart[w] + (x - v);
        running += wpart[16];
        __syncthreads();
    }
    if (tid == 0) off[n] = running;
}

// ---------------- dinv ----------------
__global__ __launch_bounds__(256) void dinv_kernel(const int* __restrict__ deg, float* __restrict__ dinv)
{
    int n = blockIdx.x * 256 + threadIdx.x;
    if (n < N_NODES) {
        int d = deg[n];
        dinv[n] = d > 0 ? 1.0f / sqrtf((float)d) : 0.0f;
    }
}

// ---------------- CSR fill ----------------
__global__ __launch_bounds__(256) void fill_kernel(const int* __restrict__ row, const int* __restrict__ col,
                                                   const int* __restrict__ off, int* __restrict__ cursor,
                                                   const float* __restrict__ dinv,
                                                   int* __restrict__ csr_src, float* __restrict__ csr_nrm)
{
    int e = blockIdx.x * 256 + threadIdx.x;
    if (e < NEDGE) {
        int r = row[e], c = col[e];
        int p = atomicAdd(&cursor[c], 1);
        int idx = off[c] + p;
        csr_src[idx] = r;
        csr_nrm[idx] = dinv[r] * dinv[c];
    }
}

// ---------------- GEMM1: temp1 = leaky_relu(features @ mlp_w + b) ----------------
// A[50000,512] * B[512,256] -> C[50000,256], tile 128x128, BK=16, 256 thr, 8x8/thread
__global__ __launch_bounds__(256) void gemm1_kernel(const float* __restrict__ A, const float* __restrict__ B,
                                                    const float* __restrict__ bias, float* __restrict__ C)
{
    __shared__ float As[16][132];
    __shared__ float Bs[16][128];
    const int tid = threadIdx.x;
    const int tx = tid & 15, ty = tid >> 4;
    const int m0 = blockIdx.x * 128, n0 = blockIdx.y * 128;
    float acc[8][8] = {};
    for (int k0 = 0; k0 < 512; k0 += 16) {
        #pragma unroll
        for (int rep = 0; rep < 2; ++rep) {
            int idx = tid + rep * 256;
            int m = idx >> 2;
            int kc = (idx & 3) << 2;
            int row = m0 + m;
            float4 v = make_float4(0.f, 0.f, 0.f, 0.f);
            if (row < 50000) v = *(const float4*)&A[(size_t)row * 512 + k0 + kc];
            As[kc + 0][m] = v.x; As[kc + 1][m] = v.y; As[kc + 2][m] = v.z; As[kc + 3][m] = v.w;
        }
        #pragma unroll
        for (int rep = 0; rep < 2; ++rep) {
            int idx = tid + rep * 256;
            int kk = idx >> 5;
            int nc = (idx & 31) << 2;
            float4 v = *(const float4*)&B[(size_t)(k0 + kk) * 256 + n0 + nc];
            *(float4*)&Bs[kk][nc] = v;
        }
        __syncthreads();
        #pragma unroll
        for (int k = 0; k < 16; ++k) {
            float4 a0 = *(const float4*)&As[k][ty * 8];
            float4 a1 = *(const float4*)&As[k][ty * 8 + 4];
            float4 b0 = *(const float4*)&Bs[k][tx * 8];
            float4 b1 = *(const float4*)&Bs[k][tx * 8 + 4];
            float a[8] = {a0.x, a0.y, a0.z, a0.w, a1.x, a1.y, a1.z, a1.w};
            float b[8] = {b0.x, b0.y, b0.z, b0.w, b1.x, b1.y, b1.z, b1.w};
            #pragma unroll
            for (int i = 0; i < 8; ++i)
                #pragma unroll
                for (int j = 0; j < 8; ++j)
                    acc[i][j] += a[i] * b[j];
        }
        __syncthreads();
    }
    float4 bv0 = *(const float4*)&bias[n0 + tx * 8];
    float4 bv1 = *(const float4*)&bias[n0 + tx * 8 + 4];
    float bb[8] = {bv0.x, bv0.y, bv0.z, bv0.w, bv1.x, bv1.y, bv1.z, bv1.w};
    #pragma unroll
    for (int i = 0; i < 8; ++i) {
        int row = m0 + ty * 8 + i;
        if (row < 50000) {
            float o[8];
            #pragma unroll
            for (int j = 0; j < 8; ++j) {
                float t = acc[i][j] + bb[j];
                o[j] = t >= 0.f ? t : 0.01f * t;
            }
            *(float4*)&C[(size_t)row * 256 + n0 + tx * 8]     = make_float4(o[0], o[1], o[2], o[3]);
            *(float4*)&C[(size_t)row * 256 + n0 + tx * 8 + 4] = make_float4(o[4], o[5], o[6], o[7]);
        }
    }
}

// ---------------- GEMM2: temp = temp1 @ mlp1_w + b1 ----------------
// A[50000,256] * B[256,64] -> C[50000,64], tile 128x64, BK=16, 256 thr, 8x4/thread
__global__ __launch_bounds__(256) void gemm2_kernel(const float* __restrict__ A, const float* __restrict__ B,
                                                    const float* __restrict__ bias, float* __restrict__ C)
{
    __shared__ float As[16][132];
    __shared__ float Bs[16][64];
    const int tid = threadIdx.x;
    const int tx = tid & 15, ty = tid >> 4;
    const int m0 = blockIdx.x * 128;
    float acc[8][4] = {};
    for (int k0 = 0; k0 < 256; k0 += 16) {
        #pragma unroll
        for (int rep = 0; rep < 2; ++rep) {
            int idx = tid + rep * 256;
            int m = idx >> 2;
            int kc = (idx & 3) << 2;
            int row = m0 + m;
            float4 v = make_float4(0.f, 0.f, 0.f, 0.f);
            if (row < 50000) v = *(const float4*)&A[(size_t)row * 256 + k0 + kc];
            As[kc + 0][m] = v.x; As[kc + 1][m] = v.y; As[kc + 2][m] = v.z; As[kc + 3][m] = v.w;
        }
        {
            int kk = tid >> 4;
            int nc = (tid & 15) << 2;
            float4 v = *(const float4*)&B[(size_t)(k0 + kk) * 64 + nc];
            *(float4*)&Bs[kk][nc] = v;
        }
        __syncthreads();
        #pragma unroll
        for (int k = 0; k < 16; ++k) {
            float4 a0 = *(const float4*)&As[k][ty * 8];
            float4 a1 = *(const float4*)&As[k][ty * 8 + 4];
            float4 b0 = *(const float4*)&Bs[k][tx * 4];
            float a[8] = {a0.x, a0.y, a0.z, a0.w, a1.x, a1.y, a1.z, a1.w};
            float b[4] = {b0.x, b0.y, b0.z, b0.w};
            #pragma unroll
            for (int i = 0; i < 8; ++i)
                #pragma unroll
                for (int j = 0; j < 4; ++j)
                    acc[i][j] += a[i] * b[j];
        }
        __syncthreads();
    }
    float4 bv = *(const float4*)&bias[tx * 4];
    #pragma unroll
    for (int i = 0; i < 8; ++i) {
        int row = m0 + ty * 8 + i;
        if (row < 50000) {
            float4 o = make_float4(acc[i][0] + bv.x, acc[i][1] + bv.y, acc[i][2] + bv.z, acc[i][3] + bv.w);
            *(float4*)&C[(size_t)row * 64 + tx * 4] = o;
        }
    }
}

// ---------------- build x0: normalized comps, [N,256] ----------------
__global__ __launch_bounds__(256) void build_x0_kernel(const float* __restrict__ emb_s, const float* __restrict__ emb_x,
                                                       const float* __restrict__ temp, float* __restrict__ x0)
{
    int wid = (blockIdx.x * 256 + threadIdx.x) >> 6;
    int lane = threadIdx.x & 63;
    if (wid >= N_NODES) return;
    if (wid < NUM_USER) {
        #pragma unroll
        for (int a = 0; a < ALG; ++a) {
            const float* srcp = (a == 0) ? &emb_s[(size_t)wid * 64]
                                         : &emb_x[((size_t)(a - 1) * NUM_USER + wid) * 64];
            float v = srcp[lane];
            float ss = v * v;
            #pragma unroll
            for (int m = 1; m < 64; m <<= 1) ss += __shfl_xor(ss, m);
            float inv = 1.0f / fmaxf(sqrtf(ss), 1e-12f);
            x0[(size_t)wid * 256 + a * 64 + lane] = v * inv;
        }
    } else {
        float v = temp[(size_t)(wid - NUM_USER) * 64 + lane];
        float ss = v * v;
        #pragma unroll
        for (int m = 1; m < 64; m <<= 1) ss += __shfl_xor(ss, m);
        float inv = 1.0f / fmaxf(sqrtf(ss), 1e-12f);
        float r = v * inv;
        #pragma unroll
        for (int a = 0; a < ALG; ++a)
            x0[(size_t)wid * 256 + a * 64 + lane] = r;
    }
}

// ---------------- propagation: xout[n] = sum_{e: col=n} nrm[e]*xin[src[e]] (+addA+addB) ----------------
__global__ __launch_bounds__(256) void prop_kernel(const float4* __restrict__ xin, float4* __restrict__ xout,
                                                   const int* __restrict__ off, const int* __restrict__ src,
                                                   const float* __restrict__ nrm,
                                                   const float4* __restrict__ addA, const float4* __restrict__ addB)
{
    int wid = (blockIdx.x * 256 + threadIdx.x) >> 6;
    int lane = threadIdx.x & 63;
    if (wid >= N_NODES) return;
    int o0 = off[wid], o1 = off[wid + 1];
    float4 acc = make_float4(0.f, 0.f, 0.f, 0.f);
    int i = o0;
    for (; i + 1 < o1; i += 2) {
        int s0 = src[i], s1 = src[i + 1];
        float w0 = nrm[i], w1 = nrm[i + 1];
        float4 v0 = xin[(size_t)s0 * 64 + lane];
        float4 v1 = xin[(size_t)s1 * 64 + lane];
        acc.x += w0 * v0.x; acc.y += w0 * v0.y; acc.z += w0 * v0.z; acc.w += w0 * v0.w;
        acc.x += w1 * v1.x; acc.y += w1 * v1.y; acc.z += w1 * v1.z; acc.w += w1 * v1.w;
    }
    if (i < o1) {
        int s0 = src[i];
        float w0 = nrm[i];
        float4 v0 = xin[(size_t)s0 * 64 + lane];
        acc.x += w0 * v0.x; acc.y += w0 * v0.y; acc.z += w0 * v0.z; acc.w += w0 * v0.w;
    }
    size_t oi = (size_t)wid * 64 + lane;
    if (addA) {
        float4 a = addA[oi];
        float4 b = addB[oi];
        acc.x += a.x + b.x; acc.y += a.y + b.y; acc.z += a.z + b.z; acc.w += a.w + b.w;
    }
    xout[oi] = acc;
}

extern "C" void kernel_launch(void* const* d_in, const int* in_sizes, int n_in,
                              void* d_out, int out_size, void* d_ws, size_t ws_size,
                              hipStream_t stream)
{
    const int*   edge     = (const int*)d_in[0];   // [2, 1M]
    const float* features = (const float*)d_in[1]; // [50000, 512]
    const float* emb_s    = (const float*)d_in[2]; // [100000, 64]
    const float* emb_x    = (const float*)d_in[3]; // [3, 100000, 64]
    const float* prompt   = (const float*)d_in[4]; // [150000, 256]
    const float* mlp_w    = (const float*)d_in[5]; // [512, 256]
    const float* mlp_b    = (const float*)d_in[6]; // [256]
    const float* mlp1_w   = (const float*)d_in[7]; // [256, 64]
    const float* mlp1_b   = (const float*)d_in[8]; // [64]
    float*       out      = (float*)d_out;         // [150000, 256]

    const int* row = edge;
    const int* col = edge + NEDGE;

    // ---- workspace layout (floats) ----
    const size_t NX = (size_t)N_NODES * 256;      // 38.4M floats
    float* ws     = (float*)d_ws;
    float* x0     = ws;                            // [NX]
    float* x1     = ws + NX;                       // [NX]
    float* temp1  = x1;                            // [50000*256]  (dead before x1 written)
    float* temp   = x1 + (size_t)50000 * 256;      // [50000*64]
    int*   deg    = (int*)(ws + 2 * NX);           // [150016]
    int*   cursor = deg + 150016;                  // [150016]
    int*   off    = cursor + 150016;               // [150016] (need 150001)
    int*   csr_src = off + 150016;                 // [1M]
    float* csr_nrm = (float*)(csr_src + NEDGE);    // [1M]
    float* dinv    = csr_nrm + NEDGE;              // [150000]

    // zero deg + cursor (adjacent)
    hipMemsetAsync(deg, 0, 2 * 150016 * sizeof(int), stream);

    // graph preprocessing
    count_kernel<<<(NEDGE + 255) / 256, 256, 0, stream>>>(row, deg);
    scan_kernel<<<1, 1024, 0, stream>>>(deg, off, N_NODES);
    dinv_kernel<<<(N_NODES + 255) / 256, 256, 0, stream>>>(deg, dinv);
    fill_kernel<<<(NEDGE + 255) / 256, 256, 0, stream>>>(row, col, off, cursor, dinv, csr_src, csr_nrm);

    // item feature MLP
    gemm1_kernel<<<dim3(391, 2), 256, 0, stream>>>(features, mlp_w, mlp_b, temp1);
    gemm2_kernel<<<dim3(391, 1), 256, 0, stream>>>(temp1, mlp1_w, mlp1_b, temp);

    // build normalized components
    build_x0_kernel<<<N_NODES / 4, 256, 0, stream>>>(emb_s, emb_x, temp, x0);

    // layer 1: x1 = P x0
    prop_kernel<<<N_NODES / 4, 256, 0, stream>>>((const float4*)x0, (float4*)x1,
                                                 off, csr_src, csr_nrm, nullptr, nullptr);
    // layer 2 fused: out = P x1 + x1 + prompt
    prop_kernel<<<N_NODES / 4, 256, 0, stream>>>((const float4*)x1, (float4*)out,
                                                 off, csr_src, csr_nrm,
                                                 (const float4*)x1, (const float4*)prompt);
}

// Round 3
// 1012.301 us; speedup vs baseline: 1.1262x; 1.1262x over previous
//
#include <hip/hip_runtime.h>
#include <hip/hip_bf16.h>

#define NUM_USER 100000
#define NUM_ITEM 50000
#define N_NODES  150000
#define EMBED_DIM 64
#define ALG 4
#define DIM_FEAT 512
#define NEDGE 1000000

typedef __attribute__((ext_vector_type(8))) short bf16x8;
typedef __attribute__((ext_vector_type(4))) float f32x4;

// ---------------- degree count ----------------
__global__ __launch_bounds__(256) void count_kernel(const int* __restrict__ row, int* __restrict__ deg)
{
    int e = blockIdx.x * 256 + threadIdx.x;
    if (e < NEDGE) atomicAdd(&deg[row[e]], 1);
}

// ---------------- exclusive scan (single block, 1024 thr) ----------------
__global__ __launch_bounds__(1024) void scan_kernel(const int* __restrict__ deg, int* __restrict__ off, int n)
{
    __shared__ int wpart[17];
    const int tid = threadIdx.x;
    const int lane = tid & 63, w = tid >> 6;
    int running = 0;
    for (int base = 0; base < n; base += 1024) {
        int i = base + tid;
        int v = (i < n) ? deg[i] : 0;
        int x = v;
        #pragma unroll
        for (int d = 1; d < 64; d <<= 1) {
            int t = __shfl_up(x, d);
            if (lane >= d) x += t;
        }
        if (lane == 63) wpart[w] = x;
        __syncthreads();
        if (tid == 0) {
            int a = 0;
            #pragma unroll
            for (int j = 0; j < 16; ++j) { int t = wpart[j]; wpart[j] = a; a += t; }
            wpart[16] = a;
        }
        __syncthreads();
        if (i < n) off[i] = running + wpart[w] + (x - v);
        running += wpart[16];
        __syncthreads();
    }
    if (tid == 0) off[n] = running;
}

// ---------------- dinv ----------------
__global__ __launch_bounds__(256) void dinv_kernel(const int* __restrict__ deg, float* __restrict__ dinv)
{
    int n = blockIdx.x * 256 + threadIdx.x;
    if (n < N_NODES) {
        int d = deg[n];
        dinv[n] = d > 0 ? 1.0f / sqrtf((float)d) : 0.0f;
    }
}

// ---------------- CSR fill ----------------
__global__ __launch_bounds__(256) void fill_kernel(const int* __restrict__ row, const int* __restrict__ col,
                                                   const int* __restrict__ off, int* __restrict__ cursor,
                                                   const float* __restrict__ dinv,
                                                   int* __restrict__ csr_src, float* __restrict__ csr_nrm)
{
    int e = blockIdx.x * 256 + threadIdx.x;
    if (e < NEDGE) {
        int r = row[e], c = col[e];
        int p = atomicAdd(&cursor[c], 1);
        int idx = off[c] + p;
        csr_src[idx] = r;
        csr_nrm[idx] = dinv[r] * dinv[c];
    }
}

// ---------------- split a float into bf16 hi/lo (truncation trick) ----------------
__device__ __forceinline__ void split_bf16(float v, unsigned short& h, unsigned short& l)
{
    unsigned int u = __float_as_uint(v);
    unsigned int hu = u & 0xFFFF0000u;
    float lf = v - __uint_as_float(hu);
    h = (unsigned short)(u >> 16);
    l = (unsigned short)(__float_as_uint(lf) >> 16);
}

// ---------------- B conversion: B1[512,256] -> Bt1 [256][512] hi/lo; B2[256,64] -> Bt2 [64][256] hi/lo ----
__global__ __launch_bounds__(256) void convert_b_kernel(const float* __restrict__ B1, const float* __restrict__ B2,
                                                        unsigned short* __restrict__ Bt1h, unsigned short* __restrict__ Bt1l,
                                                        unsigned short* __restrict__ Bt2h, unsigned short* __restrict__ Bt2l)
{
    int i = blockIdx.x * 256 + threadIdx.x;
    if (i < 512 * 256) {
        int k = i >> 8, n = i & 255;   // B1[k][n]
        unsigned short h, l;
        split_bf16(B1[i], h, l);
        Bt1h[n * 512 + k] = h;
        Bt1l[n * 512 + k] = l;
    } else {
        int j = i - 512 * 256;
        if (j < 256 * 64) {
            int k = j >> 6, n = j & 63;   // B2[k][n]
            unsigned short h, l;
            split_bf16(B2[j], h, l);
            Bt2h[n * 256 + k] = h;
            Bt2l[n * 256 + k] = l;
        }
    }
}

// ---------------- split-bf16 MFMA GEMM ----------------
// C[M,N] = act(A[M,K] @ B[K,N] + bias), B provided pre-transposed+split as Bt[N][K] hi/lo bf16.
// Tile: BM=128, BN=NF*32 (2 wave-cols), 256 thr = 4 waves (2x2), wave tile 64 x NF*16.
// Split product: C = Ah*Bh + Ah*Bl + Al*Bh  (error ~2^-16 relative).
template<int M, int K, int N, int NF, bool LRELU>
__global__ __launch_bounds__(256) void gemm_mfma_kernel(const float* __restrict__ A,
                                                        const unsigned short* __restrict__ Bth,
                                                        const unsigned short* __restrict__ Btl,
                                                        const float* __restrict__ bias,
                                                        float* __restrict__ C)
{
    constexpr int BN = NF * 32;
    __shared__ unsigned short Ah[128][40], Al[128][40];
    __shared__ unsigned short Bh[BN][40],  Bl[BN][40];

    const int tid  = threadIdx.x;
    const int lane = tid & 63;
    const int wid  = tid >> 6;
    const int wr = wid >> 1, wc = wid & 1;
    const int fm = lane & 15;
    const int fk = (lane >> 4) * 8;
    const int m0 = blockIdx.x * 128;
    const int n0 = blockIdx.y * BN;

    // staging coords
    const int sr = tid >> 1;        // 0..127
    const int sh = tid & 1;         // k-half (0/1 -> 16 floats)

    f32x4 acc[4][NF];
    #pragma unroll
    for (int i = 0; i < 4; ++i)
        #pragma unroll
        for (int j = 0; j < NF; ++j)
            acc[i][j] = (f32x4){0.f, 0.f, 0.f, 0.f};

    for (int k0 = 0; k0 < K; k0 += 32) {
        // ---- stage A (fp32 -> hi/lo bf16) ----
        {
            int row = m0 + sr;
            float va[16];
            if (row < M) {
                const float* ap = &A[(size_t)row * K + k0 + sh * 16];
                #pragma unroll
                for (int c = 0; c < 4; ++c) {
                    float4 v = *(const float4*)&ap[c * 4];
                    va[c * 4 + 0] = v.x; va[c * 4 + 1] = v.y; va[c * 4 + 2] = v.z; va[c * 4 + 3] = v.w;
                }
            } else {
                #pragma unroll
                for (int c = 0; c < 16; ++c) va[c] = 0.f;
            }
            union { unsigned short s[16]; float4 f[2]; } uh, ul;
            #pragma unroll
            for (int c = 0; c < 16; ++c) split_bf16(va[c], uh.s[c], ul.s[c]);
            *(float4*)&Ah[sr][sh * 16]     = uh.f[0];
            *(float4*)&Ah[sr][sh * 16 + 8] = uh.f[1];
            *(float4*)&Al[sr][sh * 16]     = ul.f[0];
            *(float4*)&Al[sr][sh * 16 + 8] = ul.f[1];
        }
        // ---- stage Bt (already bf16) ----
        if (sr < BN) {
            const unsigned short* bp = &Bth[(size_t)(n0 + sr) * K + k0 + sh * 16];
            *(float4*)&Bh[sr][sh * 16]     = *(const float4*)&bp[0];
            *(float4*)&Bh[sr][sh * 16 + 8] = *(const float4*)&bp[8];
            const unsigned short* lp = &Btl[(size_t)(n0 + sr) * K + k0 + sh * 16];
            *(float4*)&Bl[sr][sh * 16]     = *(const float4*)&lp[0];
            *(float4*)&Bl[sr][sh * 16 + 8] = *(const float4*)&lp[8];
        }
        __syncthreads();

        // ---- fragments + MFMA ----
        bf16x8 fah[4], fal[4], fbh[NF], fbl[NF];
        #pragma unroll
        for (int i = 0; i < 4; ++i) {
            fah[i] = *(const bf16x8*)&Ah[wr * 64 + i * 16 + fm][fk];
            fal[i] = *(const bf16x8*)&Al[wr * 64 + i * 16 + fm][fk];
        }
        #pragma unroll
        for (int j = 0; j < NF; ++j) {
            fbh[j] = *(const bf16x8*)&Bh[wc * NF * 16 + j * 16 + fm][fk];
            fbl[j] = *(const bf16x8*)&Bl[wc * NF * 16 + j * 16 + fm][fk];
        }
        #pragma unroll
        for (int i = 0; i < 4; ++i)
            #pragma unroll
            for (int j = 0; j < NF; ++j) {
                acc[i][j] = __builtin_amdgcn_mfma_f32_16x16x32_bf16(fah[i], fbh[j], acc[i][j], 0, 0, 0);
                acc[i][j] = __builtin_amdgcn_mfma_f32_16x16x32_bf16(fah[i], fbl[j], acc[i][j], 0, 0, 0);
                acc[i][j] = __builtin_amdgcn_mfma_f32_16x16x32_bf16(fal[i], fbh[j], acc[i][j], 0, 0, 0);
            }
        __syncthreads();
    }

    // ---- epilogue: bias + activation + store ----
    // C/D layout (m89-verified): col = lane&15, row = (lane>>4)*4 + reg
    #pragma unroll
    for (int i = 0; i < 4; ++i) {
        int rbase = m0 + wr * 64 + i * 16 + (lane >> 4) * 4;
        #pragma unroll
        for (int j = 0; j < NF; ++j) {
            int col = n0 + wc * NF * 16 + j * 16 + fm;
            float bv = bias[col];
            #pragma unroll
            for (int q = 0; q < 4; ++q) {
                int r = rbase + q;
                if (r < M) {
                    float o = acc[i][j][q] + bv;
                    if (LRELU) o = o >= 0.f ? o : 0.01f * o;
                    C[(size_t)r * N + col] = o;
                }
            }
        }
    }
}

// ---------------- build x0: normalized comps, [N,256] ----------------
__global__ __launch_bounds__(256) void build_x0_kernel(const float* __restrict__ emb_s, const float* __restrict__ emb_x,
                                                       const float* __restrict__ temp, float* __restrict__ x0)
{
    int wid = (blockIdx.x * 256 + threadIdx.x) >> 6;
    int lane = threadIdx.x & 63;
    if (wid >= N_NODES) return;
    if (wid < NUM_USER) {
        #pragma unroll
        for (int a = 0; a < ALG; ++a) {
            const float* srcp = (a == 0) ? &emb_s[(size_t)wid * 64]
                                         : &emb_x[((size_t)(a - 1) * NUM_USER + wid) * 64];
            float v = srcp[lane];
            float ss = v * v;
            #pragma unroll
            for (int m = 1; m < 64; m <<= 1) ss += __shfl_xor(ss, m);
            float inv = 1.0f / fmaxf(sqrtf(ss), 1e-12f);
            x0[(size_t)wid * 256 + a * 64 + lane] = v * inv;
        }
    } else {
        float v = temp[(size_t)(wid - NUM_USER) * 64 + lane];
        float ss = v * v;
        #pragma unroll
        for (int m = 1; m < 64; m <<= 1) ss += __shfl_xor(ss, m);
        float inv = 1.0f / fmaxf(sqrtf(ss), 1e-12f);
        float r = v * inv;
        #pragma unroll
        for (int a = 0; a < ALG; ++a)
            x0[(size_t)wid * 256 + a * 64 + lane] = r;
    }
}

// ---------------- propagation: xout[n] = sum_{e: col=n} nrm[e]*xin[src[e]] (+addA+addB) ----------------
__global__ __launch_bounds__(256) void prop_kernel(const float4* __restrict__ xin, float4* __restrict__ xout,
                                                   const int* __restrict__ off, const int* __restrict__ src,
                                                   const float* __restrict__ nrm,
                                                   const float4* __restrict__ addA, const float4* __restrict__ addB)
{
    int wid = (blockIdx.x * 256 + threadIdx.x) >> 6;
    int lane = threadIdx.x & 63;
    if (wid >= N_NODES) return;
    int o0 = off[wid], o1 = off[wid + 1];
    float4 acc = make_float4(0.f, 0.f, 0.f, 0.f);
    int i = o0;
    for (; i + 1 < o1; i += 2) {
        int s0 = src[i], s1 = src[i + 1];
        float w0 = nrm[i], w1 = nrm[i + 1];
        float4 v0 = xin[(size_t)s0 * 64 + lane];
        float4 v1 = xin[(size_t)s1 * 64 + lane];
        acc.x += w0 * v0.x; acc.y += w0 * v0.y; acc.z += w0 * v0.z; acc.w += w0 * v0.w;
        acc.x += w1 * v1.x; acc.y += w1 * v1.y; acc.z += w1 * v1.z; acc.w += w1 * v1.w;
    }
    if (i < o1) {
        int s0 = src[i];
        float w0 = nrm[i];
        float4 v0 = xin[(size_t)s0 * 64 + lane];
        acc.x += w0 * v0.x; acc.y += w0 * v0.y; acc.z += w0 * v0.z; acc.w += w0 * v0.w;
    }
    size_t oi = (size_t)wid * 64 + lane;
    if (addA) {
        float4 a = addA[oi];
        float4 b = addB[oi];
        acc.x += a.x + b.x; acc.y += a.y + b.y; acc.z += a.z + b.z; acc.w += a.w + b.w;
    }
    xout[oi] = acc;
}

extern "C" void kernel_launch(void* const* d_in, const int* in_sizes, int n_in,
                              void* d_out, int out_size, void* d_ws, size_t ws_size,
                              hipStream_t stream)
{
    const int*   edge     = (const int*)d_in[0];   // [2, 1M]
    const float* features = (const float*)d_in[1]; // [50000, 512]
    const float* emb_s    = (const float*)d_in[2]; // [100000, 64]
    const float* emb_x    = (const float*)d_in[3]; // [3, 100000, 64]
    const float* prompt   = (const float*)d_in[4]; // [150000, 256]
    const float* mlp_w    = (const float*)d_in[5]; // [512, 256]
    const float* mlp_b    = (const float*)d_in[6]; // [256]
    const float* mlp1_w   = (const float*)d_in[7]; // [256, 64]
    const float* mlp1_b   = (const float*)d_in[8]; // [64]
    float*       out      = (float*)d_out;         // [150000, 256]

    const int* row = edge;
    const int* col = edge + NEDGE;

    // ---- workspace layout (floats) ----
    const size_t NX = (size_t)N_NODES * 256;      // 38.4M floats
    float* ws     = (float*)d_ws;
    float* x0     = ws;                            // [NX]
    float* x1     = ws + NX;                       // [NX]
    float* temp1  = x1;                            // [50000*256]  (dead before x1 written)
    float* temp   = x1 + (size_t)50000 * 256;      // [50000*64]
    int*   deg    = (int*)(ws + 2 * NX);           // [150016]
    int*   cursor = deg + 150016;                  // [150016]
    int*   off    = cursor + 150016;               // [150016] (need 150001)
    int*   csr_src = off + 150016;                 // [1M]
    float* csr_nrm = (float*)(csr_src + NEDGE);    // [1M]
    float* dinv    = csr_nrm + NEDGE;              // [150000]

    // Bt split buffers live at the START of x0 (dead until build_x0 runs)
    unsigned short* Bt1h = (unsigned short*)x0;    // [256*512]
    unsigned short* Bt1l = Bt1h + 256 * 512;
    unsigned short* Bt2h = Bt1l + 256 * 512;       // [64*256]
    unsigned short* Bt2l = Bt2h + 64 * 256;

    // zero deg + cursor (adjacent)
    hipMemsetAsync(deg, 0, 2 * 150016 * sizeof(int), stream);

    // B transpose+split (tiny)
    convert_b_kernel<<<576, 256, 0, stream>>>(mlp_w, mlp1_w, Bt1h, Bt1l, Bt2h, Bt2l);

    // graph preprocessing
    count_kernel<<<(NEDGE + 255) / 256, 256, 0, stream>>>(row, deg);
    scan_kernel<<<1, 1024, 0, stream>>>(deg, off, N_NODES);
    dinv_kernel<<<(N_NODES + 255) / 256, 256, 0, stream>>>(deg, dinv);
    fill_kernel<<<(NEDGE + 255) / 256, 256, 0, stream>>>(row, col, off, cursor, dinv, csr_src, csr_nrm);

    // item feature MLP on matrix cores (split-bf16, fp32-accurate)
    gemm_mfma_kernel<50000, 512, 256, 4, true ><<<dim3(391, 2), 256, 0, stream>>>(features, Bt1h, Bt1l, mlp_b, temp1);
    gemm_mfma_kernel<50000, 256,  64, 2, false><<<dim3(391, 1), 256, 0, stream>>>(temp1,    Bt2h, Bt2l, mlp1_b, temp);

    // build normalized components
    build_x0_kernel<<<N_NODES / 4, 256, 0, stream>>>(emb_s, emb_x, temp, x0);

    // layer 1: x1 = P x0
    prop_kernel<<<N_NODES / 4, 256, 0, stream>>>((const float4*)x0, (float4*)x1,
                                                 off, csr_src, csr_nrm, nullptr, nullptr);
    // layer 2 fused: out = P x1 + x1 + prompt
    prop_kernel<<<N_NODES / 4, 256, 0, stream>>>((const float4*)x1, (float4*)out,
                                                 off, csr_src, csr_nrm,
                                                 (const float4*)x1, (const float4*)prompt);
}